// Round 16
// baseline (22301.201 us; speedup 1.0000x reference)
//
#include <hip/hip_runtime.h>
#include <math.h>

#define NBLK    32          // worker blocks, all on ONE XCD (its 32 CUs)
#define NLAUNCH 256         // launched blocks; non-elected exit immediately
#define BS      512
#define NSTATE  17
#define NH      256
#define NX      273         // NH + NSTATE
#define WID     1024
#define NT      64
#define NSUB    8
#define SLC     32          // activation slice per block = WID/NBLK
#define POLL_CAP 500000     // fail fast instead of hanging

// packed partial word: {cnt:8 | (q0+B):28 | (q1+B):28}, q = round(p * 2^15)
// R16: 4 replicas/word, 8 adds each: 8*(q+B) < 2^25 per field, no carry.
#define SCALE_P 32768.0f
#define INV_P   3.0517578125e-5f
#define BIAS_P  (1LL << 22)
#define BIAS32  (32LL << 22)

typedef unsigned long long u64;
typedef unsigned int u32;

__device__ __forceinline__ float softplus_f(float v) {
    return fmaxf(v, 0.f) + log1pf(expf(-fabsf(v)));
}

// ---- counter-embedded fixed-point accumulate exchange (same-XCD L2) -------
// Col-parallel partial sums via L2 atomic units (never stale, deterministic;
// R5-R15-proven). R15 analysis: RMW COUNT is exhausted; the fixed per-sync
// cost remains, and its one reducible term is the 32-deep SAME-ADDRESS add
// chain serializing at one atomic unit. R16: 4-way REPLICATED accumulators
// (block b -> replica b&3): chain 32->8, adds unchanged, residency intact.
// Consumer polls all 4 replicas in one pipelined 4-RMW round (single
// vmcnt(0)), needs cnt==8 in EACH, sums integer fields (associative), bias
// 32*B total. dh fence: all-4-replicas cnt==8 <=> all 32 blocks arrived.
__device__ __forceinline__ void acc_pack(u64* p, float p0, float p1) {
    long long q0 = llrintf(p0 * SCALE_P) + BIAS_P;
    long long q1 = llrintf(p1 * SCALE_P) + BIAS_P;
    u64 w = 1ULL + ((u64)q0 << 8) + ((u64)q1 << 36);
    asm volatile("global_atomic_add_x2 %0, %1, off" :: "v"(p), "v"(w) : "memory");
}
__device__ __forceinline__ void rmw_read4(const u64* p, int stride,
                                          u64& w0, u64& w1, u64& w2, u64& w3) {
    const u64 *p0 = p, *p1 = p + stride, *p2 = p + 2 * stride, *p3 = p + 3 * stride;
    asm volatile("global_atomic_add_x2 %0, %4, %8, off sc0\n\t"
                 "global_atomic_add_x2 %1, %5, %8, off sc0\n\t"
                 "global_atomic_add_x2 %2, %6, %8, off sc0\n\t"
                 "global_atomic_add_x2 %3, %7, %8, off sc0\n\t"
                 "s_waitcnt vmcnt(0)"
                 : "=&v"(w0), "=&v"(w1), "=&v"(w2), "=&v"(w3)
                 : "v"(p0), "v"(p1), "v"(p2), "v"(p3), "v"(0ULL)
                 : "memory");
}
__device__ __forceinline__ void reset_async(u64* p) {   // no fence: parity-safe
    asm volatile("global_atomic_swap_x2 %0, %1, off" :: "v"(p), "v"(0ULL) : "memory");
}
// poll 4 replicas until each cnt==8; returns summed value fields (long long)
__device__ __forceinline__ void poll8x4(const u64* p, int stride,
                                        long long& v0, long long& v1) {
    u64 w0, w1, w2, w3; int it = 0;
    for (;;) {
        rmw_read4(p, stride, w0, w1, w2, w3);
        if (((w0 & 0xFFu) == 8u) & ((w1 & 0xFFu) == 8u) &
            ((w2 & 0xFFu) == 8u) & ((w3 & 0xFFu) == 8u)) break;
        if (++it > POLL_CAP) break;
    }
    long long f0 = (long long)((w0 >> 8) & 0xFFFFFFFULL)
                 + (long long)((w1 >> 8) & 0xFFFFFFFULL)
                 + (long long)((w2 >> 8) & 0xFFFFFFFULL)
                 + (long long)((w3 >> 8) & 0xFFFFFFFULL);
    long long f1 = (long long)(w0 >> 36) + (long long)(w1 >> 36)
                 + (long long)(w2 >> 36) + (long long)(w3 >> 36);
    v0 = f0 - BIAS32;
    v1 = f1 - BIAS32;
}

extern "C" __global__ __launch_bounds__(BS, 1) void ode_kernel(
    const float* __restrict__ ts,   const float* __restrict__ W0,
    const float* __restrict__ b0,   const float* __restrict__ Wh,
    const float* __restrict__ bh,   const float* __restrict__ Wl,
    const float* __restrict__ bl,   const float* __restrict__ betaW,
    const float* __restrict__ betab,const float* __restrict__ hvec,
    const float* __restrict__ scale,const float* __restrict__ y0log,
    float* __restrict__ out, u64* hacc1, u64* hacc2, u64* hacc3,
    u64* dhacc, unsigned* ctrl)
{
    const int t = threadIdx.x;

    __shared__ int role_sh;
    __shared__ __align__(16) float y_s[NX];
    __shared__ __align__(16) float yn_s[NX];
    __shared__ __align__(16) float xm[NX];    // MLP order: [h(256), state(17)]
    __shared__ __align__(16) float k_s[NX];
    __shared__ __align__(16) float z1_s[SLC];
    __shared__ __align__(16) float h1_s[SLC];
    __shared__ __align__(16) float h2_s[SLC];
    __shared__ __align__(16) float h3_s[SLC];
    __shared__ float red[8];
    __shared__ float dt_sh;
    extern __shared__ float wh3c[];  // 128KB: col-major [j][r] = Wh[2][r][blk*32+j]

    // ---- XCD election (MALL atomics, one-time): first XCD with NBLK blocks
    // wins. ~134KB LDS -> 1 block/CU; all 256 launched blocks co-resident.
    if (t == 0) {
        int xcd;
        asm volatile("s_getreg_b32 %0, hwreg(HW_REG_XCC_ID)" : "=s"(xcd));
        xcd &= 7;
        unsigned rk = atomicAdd(&ctrl[xcd], 1u);
        if (rk == NBLK - 1) atomicCAS(&ctrl[8], 0u, (unsigned)(xcd + 1));
        unsigned w; int it = 0;
        do {
            w = __hip_atomic_load(&ctrl[8], __ATOMIC_RELAXED, __HIP_MEMORY_SCOPE_AGENT);
        } while (w == 0u && ++it < 2000000);
        role_sh = (w != 0u && xcd == (int)w - 1 && rk < NBLK) ? (int)rk : -1;
    }
    __syncthreads();
    const int blk = role_sh;
    if (blk < 0) return;

    const float scale0 = scale[0];
    const float betab0 = betab[0];

    const int rowH = t >> 4, laneH = t & 15;   // 32 rows x 16 lanes (z1 only)
    const int growH = blk * SLC + rowH;
    const int r0 = 2 * t, r1 = 2 * t + 1;      // packed output-row pair
    const int rep = blk & 3;                   // replica index for adds

    // ---- loop-invariant scalars ----
    const float b0r    = b0[growH];
    const float betaWr = (t < NH) ? betaW[t] : 0.f;
    float bl0 = 0.f, bl1 = 0.f;                // dh biases for rows 2t, 2t+1
    if (t < 128) { bl0 = bl[2 * t]; bl1 = bl[2 * t + 1]; }
    float bhc[3], bhc_o[3];
    if (t < 16) {
        bhc[0]   = bh[blk * SLC + 2 * t];
        bhc_o[0] = bh[blk * SLC + 2 * t + 1];
        bhc[1]   = bh[WID + blk * SLC + 2 * t];
        bhc_o[1] = bh[WID + blk * SLC + 2 * t + 1];
        bhc[2]   = bh[2 * WID + blk * SLC + 2 * t];
        bhc_o[2] = bh[2 * WID + blk * SLC + 2 * t + 1];
    }

    // ---- weights ----
    float w0r[18];     // W0 row-slice (z1 local)
    {
        const float* w0p = W0 + (size_t)growH * NX;
        #pragma unroll
        for (int i = 0; i < 18; i++) {
            int c = laneH + i * 16;
            w0r[i] = (c < NX) ? w0p[c] : 0.f;
        }
    }
    // h1/h2 COLUMN stripes in VGPRs: thread t owns rows {2t, 2t+1},
    // cols [blk*32,+32): 4x8 float4 = exactly 128 VGPR (residency-critical).
    float4 wc1a[8], wc1b[8], wc2a[8], wc2b[8];
    {
        const float* base0 = Wh + (size_t)r0 * WID + blk * SLC;
        const float* base1 = Wh + (size_t)r1 * WID + blk * SLC;
        #pragma unroll
        for (int q = 0; q < 8; q++) {
            wc1a[q] = *(const float4*)(base0 + q * 4);
            wc1b[q] = *(const float4*)(base1 + q * 4);
            wc2a[q] = *(const float4*)(base0 + (size_t)WID * WID + q * 4);
            wc2b[q] = *(const float4*)(base1 + (size_t)WID * WID + q * 4);
        }
    }
    // h3 column stripe in LDS, col-major [j][r]
    {
        const float* src = Wh + 2 * (size_t)WID * WID;
        for (int i = t; i < WID * 8; i += BS) {
            int r = i >> 3, q = i & 7;
            float4 v = *(const float4*)(src + (size_t)r * WID + blk * SLC + q * 4);
            wh3c[(q * 4 + 0) * WID + r] = v.x;
            wh3c[(q * 4 + 1) * WID + r] = v.y;
            wh3c[(q * 4 + 2) * WID + r] = v.z;
            wh3c[(q * 4 + 3) * WID + r] = v.w;
        }
    }

    // ---- y0 = [softmax(y0_log), hvec] ----
    if (t < NSTATE) {
        float m = -1e30f;
        for (int j = 0; j < NSTATE; j++) m = fmaxf(m, y0log[j]);
        float ssum = 0.f;
        for (int j = 0; j < NSTATE; j++) ssum += expf(y0log[j] - m);
        y_s[t] = expf(y0log[t] - m) / ssum;
    }
    if (t < NH) y_s[NSTATE + t] = hvec[t];
    __syncthreads();

    if (blk == 0) {
        if (t < NSTATE) out[t] = y_s[t];
        if (t < NH)     out[NT * NSTATE + t] = y_s[NSTATE + t];
    }

    const float c_xi = 13.f / 12.f, c_mu = 0.041f / 12.f, c_sig = 91.f / 12.f,
                c_nu = 36.f / 12.f, c_gam = 1.8f / 12.f;

    unsigned sidx = 0;       // global stage counter (parity selector)

    for (int iv = 0; iv < NT - 1; iv++) {
        if (t == 0) dt_sh = (ts[iv + 1] - ts[iv]) * (1.f / NSUB);
        __syncthreads();
        const float dt = dt_sh;

        for (int sub = 0; sub < NSUB; sub++) {
            if (t < NX) yn_s[t] = y_s[t];

            for (int s = 0; s < 4; s++) {
                const float a   = (s == 0) ? 0.f : ((s == 3) ? 1.f : 0.5f);
                const float wgt = ((s == 0) || (s == 3)) ? dt * (1.f / 6.f) : dt * (1.f / 3.f);
                const float adt = a * dt;
                ++sidx;
                const int par = (int)(sidx & 1u);       // parity buffer select
                // parity block = 4 replicas x 512 (h) / 4 x 128 (dh)
                u64* h1p = hacc1 + par * 2048;
                u64* h2p = hacc2 + par * 2048;
                u64* h3p = hacc3 + par * 2048;
                u64* dhp = dhacc + par * 512;
                u64* dhq = dhacc + (par ^ 1) * 512;     // prev parity (reset)

                // ---- stage input, built directly in MLP order [h, state] ----
                if (t < NX) {
                    const int src = (t < NH) ? (NSTATE + t) : (t - NH);
                    float v = y_s[src];
                    if (s != 0) v = fmaf(adt, k_s[src], v);
                    xm[t] = v;
                }
                __syncthreads();                                   // B1

                // ---- z1 slice (local): 32 rows x 16 lanes ----
                {
                    float acc = 0.f;
                    #pragma unroll
                    for (int i = 0; i < 18; i++) {
                        int c = laneH + i * 16;
                        if (c < NX) acc = fmaf(w0r[i], xm[c], acc);
                    }
                    #pragma unroll
                    for (int m = 1; m < 16; m <<= 1) acc += __shfl_xor(acc, m, 16);
                    if (laneH == 0) z1_s[rowH] = softplus_f(acc + b0r);
                }
                if (t < NH) {      // beta head partial
                    float p = betaWr * xm[t];
                    #pragma unroll
                    for (int m = 1; m < 64; m <<= 1) p += __shfl_xor(p, m, 64);
                    if ((t & 63) == 0) red[t >> 6] = p;
                }
                __syncthreads();                                   // B2

                // ---- h1 packed partial adds (replica rep, chain depth 8) ----
                {
                    float p0 = 0.f, p1 = 0.f;
                    #pragma unroll
                    for (int q = 0; q < 8; q++) {
                        float4 z = *(const float4*)(z1_s + q * 4);
                        p0 = fmaf(wc1a[q].x, z.x, p0); p0 = fmaf(wc1a[q].y, z.y, p0);
                        p0 = fmaf(wc1a[q].z, z.z, p0); p0 = fmaf(wc1a[q].w, z.w, p0);
                        p1 = fmaf(wc1b[q].x, z.x, p1); p1 = fmaf(wc1b[q].y, z.y, p1);
                        p1 = fmaf(wc1b[q].z, z.z, p1); p1 = fmaf(wc1b[q].w, z.w, p1);
                    }
                    acc_pack(h1p + rep * 512 + t, p0, p1);
                }

                // ---- dstate (redundant, one thread; overlaps h1 flight) ----
                if (t == 256) {
                    const float* xs = xm + NH;
                    float sd  = red[0] + red[1] + red[2] + red[3] + betab0;
                    float bb1 = 8.f / (1.f + expf(-sd)) + 25.f;
                    float bb2 = 0.5f * bb1, bb3 = 0.35f * bb1, bb4 = 0.25f * bb1;
                    float M  = xs[0],  S1 = xs[1],  E1 = xs[2],  E2 = xs[3];
                    float E3 = xs[4],  E4 = xs[5],  I1 = xs[6],  I2 = xs[7];
                    float I3 = xs[8],  I4 = xs[9],  R1 = xs[10], R2 = xs[11];
                    float R3 = xs[12], R4 = xs[13], S2 = xs[14], S3 = xs[15];
                    float S4 = xs[16];
                    float I = I1 + I2 + I3 + I4, Rs = R1 + R2 + R3 + R4;
                    k_s[0]  = Rs * c_mu - (c_xi + c_mu) * M;
                    k_s[1]  = c_mu * (1.f - Rs) + c_xi * M - c_mu * S1 - bb1 * I * S1;
                    k_s[2]  = bb1 * I * S1 - (c_mu + c_sig) * E1;
                    k_s[3]  = bb2 * I * S2 - (c_mu + c_sig) * E2;
                    k_s[4]  = bb3 * I * S3 - (c_mu + c_sig) * E3;
                    k_s[5]  = bb4 * I * S4 - (c_mu + c_sig) * E4;
                    k_s[6]  = c_sig * E1 - (c_nu + c_mu) * I1;
                    k_s[7]  = c_sig * E2 - (c_nu + c_mu) * I2;
                    k_s[8]  = c_sig * E3 - (c_nu + c_mu) * I3;
                    k_s[9]  = c_sig * E4 - (c_nu + c_mu) * I4;
                    k_s[10] = c_nu * I1 - (c_mu + c_gam) * R1;
                    k_s[11] = c_nu * I2 - (c_mu + c_gam) * R2;
                    k_s[12] = c_nu * I3 - (c_mu + c_gam) * R3;
                    k_s[13] = c_nu * I4 - (c_mu + c_gam) * R4;
                    k_s[14] = c_gam * R1 - c_mu * S2 - bb2 * I * S2;
                    k_s[15] = c_gam * R2 - c_mu * S3 - bb3 * I * S3;
                    k_s[16] = c_gam * (R3 + R4) - c_mu * S4 - bb4 * I * S4;
                }

                // ---- h1 consume (4 replicas) + deferred dh reset ----
                if (t < 16) {
                    long long v0, v1;
                    poll8x4(h1p + blk * 16 + t, 512, v0, v1);
                    #pragma unroll
                    for (int r = 0; r < 4; r++) reset_async(h1p + r * 512 + blk * 16 + t);
                    // all-replicas cnt==8 => all blocks past last stage's dh reads
                    reset_async(dhq + (t >> 2) * 128 + blk * 4 + (t & 3));
                    h1_s[2 * t]     = softplus_f((float)v0 * INV_P + bhc[0]);
                    h1_s[2 * t + 1] = softplus_f((float)v1 * INV_P + bhc_o[0]);
                }
                __syncthreads();                                   // B3

                // ---- h2 packed adds + consume ----
                {
                    float p0 = 0.f, p1 = 0.f;
                    #pragma unroll
                    for (int q = 0; q < 8; q++) {
                        float4 z = *(const float4*)(h1_s + q * 4);
                        p0 = fmaf(wc2a[q].x, z.x, p0); p0 = fmaf(wc2a[q].y, z.y, p0);
                        p0 = fmaf(wc2a[q].z, z.z, p0); p0 = fmaf(wc2a[q].w, z.w, p0);
                        p1 = fmaf(wc2b[q].x, z.x, p1); p1 = fmaf(wc2b[q].y, z.y, p1);
                        p1 = fmaf(wc2b[q].z, z.z, p1); p1 = fmaf(wc2b[q].w, z.w, p1);
                    }
                    acc_pack(h2p + rep * 512 + t, p0, p1);
                }
                if (t < 16) {
                    long long v0, v1;
                    poll8x4(h2p + blk * 16 + t, 512, v0, v1);
                    #pragma unroll
                    for (int r = 0; r < 4; r++) reset_async(h2p + r * 512 + blk * 16 + t);
                    h2_s[2 * t]     = softplus_f((float)v0 * INV_P + bhc[1]);
                    h2_s[2 * t + 1] = softplus_f((float)v1 * INV_P + bhc_o[1]);
                }
                __syncthreads();                                   // B4

                // ---- h3 packed adds (weights from LDS, col-major) ----
                {
                    float p0 = 0.f, p1 = 0.f;
                    #pragma unroll
                    for (int j = 0; j < SLC; j++) {
                        float hv = h2_s[j];
                        float2 wv = *(const float2*)(wh3c + j * WID + r0);
                        p0 = fmaf(wv.x, hv, p0);
                        p1 = fmaf(wv.y, hv, p1);
                    }
                    acc_pack(h3p + rep * 512 + t, p0, p1);
                }
                // Wl stripe prefetch (t<256): row t, cols [blk*32,+32) — as R12
                float4 wvL[8];
                if (t < NH) {
                    const float* wp = Wl + (size_t)t * WID + blk * SLC;
                    #pragma unroll
                    for (int q = 0; q < 8; q++) wvL[q] = *(const float4*)(wp + q * 4);
                }
                if (t < 16) {
                    long long v0, v1;
                    poll8x4(h3p + blk * 16 + t, 512, v0, v1);
                    #pragma unroll
                    for (int r = 0; r < 4; r++) reset_async(h3p + r * 512 + blk * 16 + t);
                    h3_s[2 * t]     = softplus_f((float)v0 * INV_P + bhc[2]);
                    h3_s[2 * t + 1] = softplus_f((float)v1 * INV_P + bhc_o[2]);
                }
                __syncthreads();                                   // B5

                // ---- dh: per-row partials (t<256), pair-merged via width-2
                //      shfl, even threads add to replica rep (chain 8) ----
                if (t < NH) {
                    float p = 0.f;
                    #pragma unroll
                    for (int q = 0; q < 8; q++) {
                        float4 z = *(const float4*)(h3_s + q * 4);
                        p = fmaf(wvL[q].x, z.x, p); p = fmaf(wvL[q].y, z.y, p);
                        p = fmaf(wvL[q].z, z.z, p); p = fmaf(wvL[q].w, z.w, p);
                    }
                    float po = __shfl_xor(p, 1, 2);      // partner row's partial
                    if ((t & 1) == 0) acc_pack(dhp + rep * 128 + (t >> 1), p, po);
                }
                // consume: t<128 polls its packed word across 4 replicas
                if (t < 128) {
                    long long v0, v1;
                    poll8x4(dhp + t, 128, v0, v1);
                    float a0 = (float)v0 * INV_P, a1 = (float)v1 * INV_P;
                    k_s[NSTATE + 2 * t]     = scale0 * tanhf(0.01f * (a0 + bl0));
                    k_s[NSTATE + 2 * t + 1] = scale0 * tanhf(0.01f * (a1 + bl1));
                }
                __syncthreads();                                   // B6
                if (t < NX) yn_s[t] = fmaf(wgt, k_s[t], yn_s[t]);
            } // stages

            __syncthreads();
            if (t < NX) y_s[t] = yn_s[t];
            __syncthreads();
        } // substeps

        if (blk == 0) {
            if (t < NSTATE) out[(iv + 1) * NSTATE + t] = y_s[t];
            if (t < NH)     out[NT * NSTATE + (iv + 1) * NH + t] = y_s[NSTATE + t];
        }
    } // intervals
}

extern "C" void kernel_launch(void* const* d_in, const int* in_sizes, int n_in,
                              void* d_out, int out_size, void* d_ws, size_t ws_size,
                              hipStream_t stream) {
    const float* ts    = (const float*)d_in[0];
    const float* W0    = (const float*)d_in[1];
    const float* b0    = (const float*)d_in[2];
    const float* Wh    = (const float*)d_in[3];
    const float* bh    = (const float*)d_in[4];
    const float* Wl    = (const float*)d_in[5];
    const float* bl    = (const float*)d_in[6];
    const float* betaW = (const float*)d_in[7];
    const float* betab = (const float*)d_in[8];
    const float* hvec  = (const float*)d_in[9];
    const float* scale = (const float*)d_in[10];
    const float* y0log = (const float*)d_in[11];
    float* out = (float*)d_out;

    // parity-doubled, 4-replica packed accumulators
    u64*      hacc1 = (u64*)d_ws;                         // 2x4x512 u64 = 32 KB
    u64*      hacc2 = (u64*)((char*)d_ws + 32768);        // 32 KB
    u64*      hacc3 = (u64*)((char*)d_ws + 65536);        // 32 KB
    u64*      dhacc = (u64*)((char*)d_ws + 98304);        // 2x4x128 u64 = 8 KB
    unsigned* ctrl  = (unsigned*)((char*)d_ws + 106496);  // cnt[8], winner

    // allow 128KB dynamic LDS (h3 column-stripe weights)
    static int lds_set = 0;
    if (!lds_set) {
        hipFuncSetAttribute((const void*)ode_kernel,
                            hipFuncAttributeMaxDynamicSharedMemorySize, 131072);
        lds_set = 1;
    }

    // zero accumulators + counters + election state
    hipMemsetAsync(d_ws, 0, 106496 + 64, stream);
    hipLaunchKernelGGL(ode_kernel, dim3(NLAUNCH), dim3(BS), 131072, stream,
                       ts, W0, b0, Wh, bh, Wl, bl, betaW, betab, hvec, scale,
                       y0log, out, hacc1, hacc2, hacc3, dhacc, ctrl);
}